// Round 11
// baseline (260.647 us; speedup 1.0000x reference)
//
#include <hip/hip_runtime.h>
#include <hip/hip_fp16.h>

#define HC 128
#define FIN 128
#define NHEAD 4
#define NS_ATT 0.2f
#define NS_ACT 0.01f
#define NBLK_P 256      // partition blocks (k_hw/k_part chunking)
#define BCAP 14336      // LDS csr-segment capacity (ints) in k_build

typedef _Float16 half8 __attribute__((ext_vector_type(8)));
typedef float f32x4 __attribute__((ext_vector_type(4)));

__device__ __forceinline__ float lrelu(float v, float s) { return v >= 0.f ? v : s * v; }

__device__ __forceinline__ int lowerb(const int* __restrict__ a, int n, int v) {
  int lo = 0, hi = n;
  while (lo < hi) {
    int m = (lo + hi) >> 1;
    if (a[m] < v) lo = m + 1; else hi = m;
  }
  return lo;
}

// fused: blocks [0,NBLK_P) = per-block bucket histogram (bucket = d>>9);
//        blocks [NBLK_P, NBLK_P+9) = W pre-swizzle into fp16 MFMA B-frags
//        (+ appended W@att_src / W@att_dst columns as N-tile 8).
__global__ __launch_bounds__(256) void k_hw(
    const int* __restrict__ ei, int* __restrict__ hist, int E, int NBUCK, int CH,
    const float* __restrict__ W, const float* __restrict__ att_s,
    const float* __restrict__ att_d, _Float16* __restrict__ Wh) {
  if (blockIdx.x >= NBLK_P) {
    const int nt = blockIdx.x - NBLK_P, t = threadIdx.x;
    const int kt = t >> 6, l = t & 63;
    const int c = nt * 16 + (l & 15);
    const int kbase = kt * 32 + (l >> 4) * 8;
    half8 v8;
#pragma unroll
    for (int j = 0; j < 8; ++j) {
      const int k = kbase + j;
      float v = 0.f;
      if (c < 128) {
        v = W[k * HC + c];
      } else if (c < 132) {
        const int h = c - 128;
        for (int cc = 0; cc < 32; ++cc) v += W[k * HC + h * 32 + cc] * att_s[h * 32 + cc];
      } else if (c < 136) {
        const int h = c - 132;
        for (int cc = 0; cc < 32; ++cc) v += W[k * HC + h * 32 + cc] * att_d[h * 32 + cc];
      }
      v8[j] = (_Float16)v;
    }
    ((half8*)Wh)[(nt * 4 + kt) * 64 + l] = v8;
    return;
  }
  __shared__ int lc[512];
  for (int i = threadIdx.x; i < NBUCK; i += 256) lc[i] = 0;
  __syncthreads();
  const int e0 = blockIdx.x * CH, e1 = min(E, e0 + CH);
  for (int e = e0 + threadIdx.x; e < e1; e += 256) {
    atomicAdd(&lc[ei[E + e] >> 9], 1);
  }
  __syncthreads();
  for (int i = threadIdx.x; i < NBUCK; i += 256) hist[i * NBLK_P + blockIdx.x] = lc[i];
}

// MFMA GEMM: xh = x@W (fp16) + a_src/a_dst from appended tile.
// Epilogue: LDS transpose -> 4 coalesced 256B row stores per wave.
__global__ __launch_bounds__(256) void k_xw(
    const float* __restrict__ x, const _Float16* __restrict__ Wh,
    _Float16* __restrict__ xh, float* __restrict__ a_src, float* __restrict__ a_dst,
    int N) {
  __shared__ _Float16 xs[4][16][HC + 8];
  const int wv = threadIdx.x >> 6, l = threadIdx.x & 63;
  const int r0 = blockIdx.x * 64 + wv * 16;
  if (r0 >= N) return;
  const int row_a = r0 + (l & 15);
  const long arow = (long)min(row_a, N - 1) * FIN;
  const int kg = (l >> 4) * 8;
  half8 afr[4];
#pragma unroll
  for (int kt = 0; kt < 4; ++kt) {
    const float4 p0 = *(const float4*)(x + arow + kt * 32 + kg);
    const float4 p1 = *(const float4*)(x + arow + kt * 32 + kg + 4);
    afr[kt][0] = (_Float16)p0.x; afr[kt][1] = (_Float16)p0.y;
    afr[kt][2] = (_Float16)p0.z; afr[kt][3] = (_Float16)p0.w;
    afr[kt][4] = (_Float16)p1.x; afr[kt][5] = (_Float16)p1.y;
    afr[kt][6] = (_Float16)p1.z; afr[kt][7] = (_Float16)p1.w;
  }
  const half8* __restrict__ Wh8 = (const half8*)Wh;
  const int rloc = (l >> 4) * 4;          // local row base of this lane's C frags
  const int cc = l & 15;
#pragma unroll
  for (int nt = 0; nt < 9; ++nt) {
    half8 b0 = Wh8[(nt * 4 + 0) * 64 + l];
    half8 b1 = Wh8[(nt * 4 + 1) * 64 + l];
    half8 b2 = Wh8[(nt * 4 + 2) * 64 + l];
    half8 b3 = Wh8[(nt * 4 + 3) * 64 + l];
    f32x4 acc = {0.f, 0.f, 0.f, 0.f};
    acc = __builtin_amdgcn_mfma_f32_16x16x32_f16(afr[0], b0, acc, 0, 0, 0);
    acc = __builtin_amdgcn_mfma_f32_16x16x32_f16(afr[1], b1, acc, 0, 0, 0);
    acc = __builtin_amdgcn_mfma_f32_16x16x32_f16(afr[2], b2, acc, 0, 0, 0);
    acc = __builtin_amdgcn_mfma_f32_16x16x32_f16(afr[3], b3, acc, 0, 0, 0);
    if (nt < 8) {
      const int col = nt * 16 + cc;
#pragma unroll
      for (int r = 0; r < 4; ++r) xs[wv][rloc + r][col] = (_Float16)acc[r];
    } else if (cc < 8) {
      float* __restrict__ dst = (cc < 4) ? a_src : a_dst;
      const int h = cc & 3;
#pragma unroll
      for (int r = 0; r < 4; ++r) {
        const int row = r0 + rloc + r;
        if (row < N) dst[row * NHEAD + h] = acc[r];
      }
    }
  }
  // coalesced stores: 4 rows per instr, 16 lanes x 16B per row
#pragma unroll
  for (int i = 0; i < 4; ++i) {
    const int lr = (l >> 4) + i * 4;
    const int row = r0 + lr;
    if (row < N) {
      const uint4 v = *(const uint4*)&xs[wv][lr][(l & 15) * 8];
      *(uint4*)(xh + (long)row * HC + (l & 15) * 8) = v;
    }
  }
}

// single-block exclusive scan: offs[i] = sum_{j<i} data[j]; offs[M] = total.
__global__ __launch_bounds__(1024) void k_scan1(const int* __restrict__ data,
                                                int* __restrict__ offs, int M) {
  __shared__ int s[1024];
  const int t = threadIdx.x;
  const int CHK = (M + 1023) >> 10;
  const int lo = t * CHK, hi = min(M, lo + CHK);
  int sum = 0;
  for (int i = lo; i < hi; ++i) sum += data[i];
  s[t] = sum;
  for (int off = 1; off < 1024; off <<= 1) {
    __syncthreads();
    int u = (t >= off) ? s[t - off] : 0;
    __syncthreads();
    s[t] += u;
  }
  __syncthreads();
  int pre = s[t] - sum;
  for (int i = lo; i < hi; ++i) {
    const int v = data[i];
    offs[i] = pre;
    pre += v;
  }
  if (t == 1023) offs[M] = s[1023];
}

// partition edges into dst-buckets; per-(block,bucket) runs exact (scanned hist)
__global__ __launch_bounds__(256) void k_part(const int* __restrict__ ei,
                                              const int* __restrict__ histoffs,
                                              unsigned* __restrict__ ebuf,
                                              int E, int NBUCK, int CH) {
  __shared__ int lcur[512];
  for (int i = threadIdx.x; i < NBUCK; i += 256)
    lcur[i] = histoffs[i * NBLK_P + blockIdx.x];
  __syncthreads();
  const int e0 = blockIdx.x * CH, e1 = min(E, e0 + CH);
  for (int e = e0 + threadIdx.x; e < e1; e += 256) {
    const int s = ei[e], d = ei[E + e];
    const int pos = atomicAdd(&lcur[d >> 9], 1);
    ebuf[pos] = ((unsigned)(d & 511) << 18) | (unsigned)s;  // N <= 262144
  }
}

// one block per bucket: per-node counts from ebuf, LDS scan -> offs, self-loops,
// LDS scatter, coalesced segment write; global fallback if segment > LDS cap.
__global__ __launch_bounds__(256) void k_build(
    const int* __restrict__ histoffs, const unsigned* __restrict__ ebuf,
    int* __restrict__ csr_src, int* __restrict__ offs, int N) {
  const int b = blockIdx.x, t = threadIdx.x;
  const int n0 = b << 9, n1 = min(N, n0 + 512), nn = n1 - n0;
  const int eb0 = histoffs[b * NBLK_P];
  const int eb1 = histoffs[(b + 1) * NBLK_P];
  const int base = eb0 + n0;
  const int L = (eb1 - eb0) + nn;
  __shared__ int cnt2[512];
  __shared__ int scn[256];
  __shared__ int cur[512];
  __shared__ int lcsr[BCAP];
  cnt2[t] = 0; cnt2[t + 256] = 0;
  __syncthreads();
  for (int e = eb0 + t; e < eb1; e += 256) atomicAdd(&cnt2[ebuf[e] >> 18], 1);
  __syncthreads();
  const int i0 = 2 * t, i1 = 2 * t + 1;
  const int a0 = (i0 < nn) ? cnt2[i0] + 1 : 0;
  const int a1 = (i1 < nn) ? cnt2[i1] + 1 : 0;
  scn[t] = a0 + a1;
  for (int off = 1; off < 256; off <<= 1) {
    __syncthreads();
    int u = (t >= off) ? scn[t - off] : 0;
    __syncthreads();
    scn[t] += u;
  }
  __syncthreads();
  const int ex = scn[t] - (a0 + a1);
  const int o0 = ex, o1 = ex + a0;
  if (i0 < nn) offs[n0 + i0] = base + o0;
  if (i1 < nn) offs[n0 + i1] = base + o1;
  if (t == 255 && n1 == N) offs[N] = base + scn[255];
  if (L <= BCAP) {
    if (i0 < nn) { lcsr[o0] = n0 + i0; cur[i0] = o0 + 1; }
    if (i1 < nn) { lcsr[o1] = n0 + i1; cur[i1] = o1 + 1; }
    __syncthreads();
    for (int e = eb0 + t; e < eb1; e += 256) {
      const unsigned pk = ebuf[e];
      const int pos = atomicAdd(&cur[pk >> 18], 1);
      lcsr[pos] = (int)(pk & 0x3FFFFu);
    }
    __syncthreads();
    for (int i = t; i < L; i += 256) csr_src[base + i] = lcsr[i];
  } else {
    if (i0 < nn) { csr_src[base + o0] = n0 + i0; cur[i0] = base + o0 + 1; }
    if (i1 < nn) { csr_src[base + o1] = n0 + i1; cur[i1] = base + o1 + 1; }
    __syncthreads();
    for (int e = eb0 + t; e < eb1; e += 256) {
      const unsigned pk = ebuf[e];
      const int pos = atomicAdd(&cur[pk >> 18], 1);
      csr_src[pos] = (int)(pk & 0x3FFFFu);
    }
  }
}

// one wave per dst node (R9 form — fetch-throughput optimum). fp16 xh gather,
// LDS-staged weights/indices, 16-edge steps w/ validity folded into weight.
__global__ __launch_bounds__(256) void k_agg(
    const int* __restrict__ csr_src, const int* __restrict__ offs,
    const float* __restrict__ a_src, const float* __restrict__ a_dst,
    const __half* __restrict__ xh, const float* __restrict__ bias,
    __half* __restrict__ xout, int N) {
  __shared__ float wls[4][64 * 5];
  __shared__ int sls[4][64];
  const int wv = threadIdx.x >> 6;
  const int wid = (blockIdx.x * 256 + threadIdx.x) >> 6;
  const int lane = threadIdx.x & 63;
  if (wid >= N) return;
  float* __restrict__ wl = wls[wv];
  int* __restrict__ sl = sls[wv];
  const int n = wid;
  const int o0 = offs[n], deg = offs[n + 1] - o0;
  const float4 dv = ((const float4*)a_dst)[n];
  const int l16 = lane & 15, g = lane >> 4, h = l16 >> 2;
  const uint4* __restrict__ xh16 = (const uint4*)xh;

  float4 sm = make_float4(0.f, 0.f, 0.f, 0.f);
  float acc[8] = {0.f, 0.f, 0.f, 0.f, 0.f, 0.f, 0.f, 0.f};

  for (int c0 = 0; c0 < deg; c0 += 64) {
    const int cl = min(64, deg - c0);
    if (lane < cl) {
      const int sj = csr_src[o0 + c0 + lane];
      const float4 av = ((const float4*)a_src)[sj];
      const float w0 = __expf(lrelu(av.x + dv.x, NS_ATT));
      const float w1 = __expf(lrelu(av.y + dv.y, NS_ATT));
      const float w2 = __expf(lrelu(av.z + dv.z, NS_ATT));
      const float w3 = __expf(lrelu(av.w + dv.w, NS_ATT));
      sm.x += w0; sm.y += w1; sm.z += w2; sm.w += w3;
      sl[lane] = sj;
      wl[lane * 5 + 0] = w0; wl[lane * 5 + 1] = w1;
      wl[lane * 5 + 2] = w2; wl[lane * 5 + 3] = w3;
    }
    for (int j = 0; j < cl; j += 16) {
      int s[4];
      float wsel[4];
      uint4 u[4];
#pragma unroll
      for (int q = 0; q < 4; ++q) {
        const int ee = j + q * 4 + g;   // always < 64
        const bool valid = ee < cl;
        const float wv_ = wl[ee * 5 + h];
        const int ss = sl[ee];
        wsel[q] = valid ? wv_ : 0.f;
        s[q] = valid ? ss : 0;
      }
#pragma unroll
      for (int q = 0; q < 4; ++q) {
        u[q] = xh16[(long)s[q] * 16 + l16];
      }
#pragma unroll
      for (int q = 0; q < 4; ++q) {
        const __half2* hp = (const __half2*)&u[q];
        const float2 f0 = __half22float2(hp[0]);
        const float2 f1 = __half22float2(hp[1]);
        const float2 f2 = __half22float2(hp[2]);
        const float2 f3 = __half22float2(hp[3]);
        acc[0] = fmaf(wsel[q], f0.x, acc[0]); acc[1] = fmaf(wsel[q], f0.y, acc[1]);
        acc[2] = fmaf(wsel[q], f1.x, acc[2]); acc[3] = fmaf(wsel[q], f1.y, acc[3]);
        acc[4] = fmaf(wsel[q], f2.x, acc[4]); acc[5] = fmaf(wsel[q], f2.y, acc[5]);
        acc[6] = fmaf(wsel[q], f3.x, acc[6]); acc[7] = fmaf(wsel[q], f3.y, acc[7]);
      }
    }
  }

#pragma unroll
  for (int m = 32; m >= 1; m >>= 1) {
    sm.x += __shfl_xor(sm.x, m);
    sm.y += __shfl_xor(sm.y, m);
    sm.z += __shfl_xor(sm.z, m);
    sm.w += __shfl_xor(sm.w, m);
  }
#pragma unroll
  for (int m = 32; m >= 16; m >>= 1) {
#pragma unroll
    for (int i = 0; i < 8; ++i) acc[i] += __shfl_xor(acc[i], m);
  }

  const float sh = (h == 0) ? sm.x : (h == 1) ? sm.y : (h == 2) ? sm.z : sm.w;
  const float inv = 1.f / (sh + 1e-16f);
  const int ch = l16 * 8 + g * 2;
  float r0 = lrelu(acc[2 * g] * inv + bias[ch], NS_ACT);
  float r1 = lrelu(acc[2 * g + 1] * inv + bias[ch + 1], NS_ACT);
  ((__half2*)(xout + (long)n * HC))[ch >> 1] = __floats2half2_rn(r0, r1);
}

// fused mean-pool + linear head: one block per graph.
__global__ __launch_bounds__(256) void k_poolfinal(
    const __half* __restrict__ xout, const int* __restrict__ batch,
    const float* __restrict__ lin_w, const float* __restrict__ lin_b,
    float* __restrict__ out, int N, int B) {
  const int b = blockIdx.x, t = threadIdx.x;
  const int lo = lowerb(batch, N, b);
  const int hi = lowerb(batch, N, b + 1);
  const int cnt = hi - lo;
  const int c2 = t & 63;     // half2 channel index
  const int rs = t >> 6;     // 4 row streams
  const __half2* __restrict__ xo2 = (const __half2*)xout;
  float ax = 0.f, ay = 0.f, bx2 = 0.f, by2 = 0.f;
  int r = lo + rs;
  for (; r + 4 < hi; r += 8) {
    float2 f0 = __half22float2(xo2[(long)r * 64 + c2]);
    float2 f1 = __half22float2(xo2[(long)(r + 4) * 64 + c2]);
    ax += f0.x; ay += f0.y; bx2 += f1.x; by2 += f1.y;
  }
  for (; r < hi; r += 4) {
    float2 f0 = __half22float2(xo2[(long)r * 64 + c2]);
    ax += f0.x; ay += f0.y;
  }
  __shared__ float2 sp[256];
  __shared__ float pl[HC];
  sp[t] = make_float2(ax + bx2, ay + by2);
  __syncthreads();
  if (t < 64) {
    float2 s0 = sp[t], s1 = sp[t + 64], s2 = sp[t + 128], s3 = sp[t + 192];
    const float c = fmaxf((float)cnt, 1.0f);
    pl[2 * t] = ((s0.x + s1.x) + (s2.x + s3.x)) / c;
    pl[2 * t + 1] = ((s0.y + s1.y) + (s2.y + s3.y)) / c;
  }
  __syncthreads();
  if (t < 10) {
    float a = lin_b[t];
    for (int k = 0; k < HC; ++k) a = fmaf(pl[k], lin_w[t * HC + k], a);
    out[b * 10 + t] = a;
  }
}

extern "C" void kernel_launch(void* const* d_in, const int* in_sizes, int n_in,
                              void* d_out, int out_size, void* d_ws, size_t ws_size,
                              hipStream_t stream) {
  const float* x = (const float*)d_in[0];
  const int* ei = (const int*)d_in[1];
  const int* batch = (const int*)d_in[2];
  const float* Wm = (const float*)d_in[4];
  const float* att_s = (const float*)d_in[5];
  const float* att_d = (const float*)d_in[6];
  const float* bias = (const float*)d_in[7];
  const float* lin_w = (const float*)d_in[8];
  const float* lin_b = (const float*)d_in[9];
  float* out = (float*)d_out;

  const int N = in_sizes[2];
  const int E = in_sizes[1] / 2;
  const int B = out_size / 10;
  const int NBUCK = (N + 511) >> 9;        // dst buckets (<=512)
  const int M = NBUCK * NBLK_P;            // hist entries
  const int CH = (E + NBLK_P - 1) / NBLK_P;

  char* p = (char*)d_ws;
  auto carve = [&](size_t bytes) {
    void* r = (void*)p;
    p += (bytes + 255) & ~(size_t)255;
    return r;
  };
  __half* xh = (__half*)carve((size_t)N * HC * 2);
  __half* xout = (__half*)carve((size_t)N * HC * 2);
  float* a_src = (float*)carve((size_t)N * NHEAD * 4);
  float* a_dst = (float*)carve((size_t)N * NHEAD * 4);
  int* offs = (int*)carve((size_t)(N + 1) * 4);
  int* csr_src = (int*)carve((size_t)(N + (size_t)E) * 4);
  _Float16* Wh = (_Float16*)carve((size_t)9 * 4 * 64 * 8 * 2);

  // alias partition scratch into xout (consumed by k_build before k_agg writes xout)
  char* q = (char*)xout;
  auto carve2 = [&](size_t bytes) {
    void* r = (void*)q;
    q += (bytes + 255) & ~(size_t)255;
    return r;
  };
  unsigned* ebuf = (unsigned*)carve2((size_t)E * 4);
  int* hist = (int*)carve2((size_t)M * 4);
  int* histoffs = (int*)carve2((size_t)(M + 1) * 4);

  k_hw<<<NBLK_P + 9, 256, 0, stream>>>(ei, hist, E, NBUCK, CH, Wm, att_s, att_d, Wh);
  k_xw<<<(N + 63) / 64, 256, 0, stream>>>(x, Wh, (_Float16*)xh, a_src, a_dst, N);
  k_scan1<<<1, 1024, 0, stream>>>(hist, histoffs, M);
  k_part<<<NBLK_P, 256, 0, stream>>>(ei, histoffs, ebuf, E, NBUCK, CH);
  k_build<<<NBUCK, 256, 0, stream>>>(histoffs, ebuf, csr_src, offs, N);
  k_agg<<<(N + 3) / 4, 256, 0, stream>>>(csr_src, offs, a_src, a_dst, xh, bias, xout, N);
  k_poolfinal<<<B, 256, 0, stream>>>(xout, batch, lin_w, lin_b, out, N, B);
}

// Round 12
// 179.425 us; speedup vs baseline: 1.4527x; 1.4527x over previous
//
#include <hip/hip_runtime.h>
#include <hip/hip_fp16.h>

#define HC 128
#define FIN 128
#define NHEAD 4
#define NS_ATT 0.2f
#define NS_ACT 0.01f
#define NBLK_P 256      // partition blocks (k_hw/k_part chunking)
#define BCAP 14336      // LDS csr-segment capacity (ints) in k_build

typedef _Float16 half8 __attribute__((ext_vector_type(8)));
typedef float f32x4 __attribute__((ext_vector_type(4)));

__device__ __forceinline__ float lrelu(float v, float s) { return v >= 0.f ? v : s * v; }

__device__ __forceinline__ int lowerb(const int* __restrict__ a, int n, int v) {
  int lo = 0, hi = n;
  while (lo < hi) {
    int m = (lo + hi) >> 1;
    if (a[m] < v) lo = m + 1; else hi = m;
  }
  return lo;
}

// fused: blocks [0,NBLK_P) = per-block bucket histogram (bucket = d>>9);
//        blocks [NBLK_P, NBLK_P+9) = W pre-swizzle into fp16 MFMA B-frags
//        (+ appended W@att_src / W@att_dst columns as N-tile 8).
__global__ __launch_bounds__(256) void k_hw(
    const int* __restrict__ ei, int* __restrict__ hist, int E, int NBUCK, int CH,
    const float* __restrict__ W, const float* __restrict__ att_s,
    const float* __restrict__ att_d, _Float16* __restrict__ Wh) {
  if (blockIdx.x >= NBLK_P) {
    const int nt = blockIdx.x - NBLK_P, t = threadIdx.x;
    const int kt = t >> 6, l = t & 63;
    const int c = nt * 16 + (l & 15);
    const int kbase = kt * 32 + (l >> 4) * 8;
    half8 v8;
#pragma unroll
    for (int j = 0; j < 8; ++j) {
      const int k = kbase + j;
      float v = 0.f;
      if (c < 128) {
        v = W[k * HC + c];
      } else if (c < 132) {
        const int h = c - 128;
        for (int cc = 0; cc < 32; ++cc) v += W[k * HC + h * 32 + cc] * att_s[h * 32 + cc];
      } else if (c < 136) {
        const int h = c - 132;
        for (int cc = 0; cc < 32; ++cc) v += W[k * HC + h * 32 + cc] * att_d[h * 32 + cc];
      }
      v8[j] = (_Float16)v;
    }
    ((half8*)Wh)[(nt * 4 + kt) * 64 + l] = v8;
    return;
  }
  __shared__ int lc[512];
  for (int i = threadIdx.x; i < NBUCK; i += 256) lc[i] = 0;
  __syncthreads();
  const int e0 = blockIdx.x * CH, e1 = min(E, e0 + CH);
  for (int e = e0 + threadIdx.x; e < e1; e += 256) {
    atomicAdd(&lc[ei[E + e] >> 9], 1);
  }
  __syncthreads();
  for (int i = threadIdx.x; i < NBUCK; i += 256) hist[i * NBLK_P + blockIdx.x] = lc[i];
}

// MFMA GEMM: xh = x@W (fp16) + a_src/a_dst from appended tile.
// Epilogue: LDS transpose -> coalesced 16B/lane row stores.
__global__ __launch_bounds__(256) void k_xw(
    const float* __restrict__ x, const _Float16* __restrict__ Wh,
    _Float16* __restrict__ xh, float* __restrict__ a_src, float* __restrict__ a_dst,
    int N) {
  __shared__ _Float16 xs[4][16][HC + 8];
  const int wv = threadIdx.x >> 6, l = threadIdx.x & 63;
  const int r0 = blockIdx.x * 64 + wv * 16;
  if (r0 >= N) return;
  const int row_a = r0 + (l & 15);
  const long arow = (long)min(row_a, N - 1) * FIN;
  const int kg = (l >> 4) * 8;
  half8 afr[4];
#pragma unroll
  for (int kt = 0; kt < 4; ++kt) {
    const float4 p0 = *(const float4*)(x + arow + kt * 32 + kg);
    const float4 p1 = *(const float4*)(x + arow + kt * 32 + kg + 4);
    afr[kt][0] = (_Float16)p0.x; afr[kt][1] = (_Float16)p0.y;
    afr[kt][2] = (_Float16)p0.z; afr[kt][3] = (_Float16)p0.w;
    afr[kt][4] = (_Float16)p1.x; afr[kt][5] = (_Float16)p1.y;
    afr[kt][6] = (_Float16)p1.z; afr[kt][7] = (_Float16)p1.w;
  }
  const half8* __restrict__ Wh8 = (const half8*)Wh;
  const int rloc = (l >> 4) * 4;
  const int cc = l & 15;
#pragma unroll
  for (int nt = 0; nt < 9; ++nt) {
    half8 b0 = Wh8[(nt * 4 + 0) * 64 + l];
    half8 b1 = Wh8[(nt * 4 + 1) * 64 + l];
    half8 b2 = Wh8[(nt * 4 + 2) * 64 + l];
    half8 b3 = Wh8[(nt * 4 + 3) * 64 + l];
    f32x4 acc = {0.f, 0.f, 0.f, 0.f};
    acc = __builtin_amdgcn_mfma_f32_16x16x32_f16(afr[0], b0, acc, 0, 0, 0);
    acc = __builtin_amdgcn_mfma_f32_16x16x32_f16(afr[1], b1, acc, 0, 0, 0);
    acc = __builtin_amdgcn_mfma_f32_16x16x32_f16(afr[2], b2, acc, 0, 0, 0);
    acc = __builtin_amdgcn_mfma_f32_16x16x32_f16(afr[3], b3, acc, 0, 0, 0);
    if (nt < 8) {
      const int col = nt * 16 + cc;
#pragma unroll
      for (int r = 0; r < 4; ++r) xs[wv][rloc + r][col] = (_Float16)acc[r];
    } else if (cc < 8) {
      float* __restrict__ dst = (cc < 4) ? a_src : a_dst;
      const int h = cc & 3;
#pragma unroll
      for (int r = 0; r < 4; ++r) {
        const int row = r0 + rloc + r;
        if (row < N) dst[row * NHEAD + h] = acc[r];
      }
    }
  }
#pragma unroll
  for (int i = 0; i < 4; ++i) {
    const int lr = (l >> 4) + i * 4;
    const int row = r0 + lr;
    if (row < N) {
      const uint4 v = *(const uint4*)&xs[wv][lr][(l & 15) * 8];
      *(uint4*)(xh + (long)row * HC + (l & 15) * 8) = v;
    }
  }
}

// hierarchical parallel scan (R10 form): A = per-block, B = partials, C = add.
__global__ void k_scanA(const int* __restrict__ cnt, int* __restrict__ offs,
                        int* __restrict__ part, int N) {
  __shared__ int s[256];
  int t = threadIdx.x, i = blockIdx.x * 256 + t;
  int v = (i < N) ? cnt[i] : 0;
  s[t] = v;
#pragma unroll
  for (int off = 1; off < 256; off <<= 1) {
    __syncthreads();
    int u = (t >= off) ? s[t - off] : 0;
    __syncthreads();
    s[t] += u;
  }
  if (i < N) offs[i] = s[t] - v;
  if (t == 255) part[blockIdx.x] = s[255];
}

__global__ void k_scanB(int* __restrict__ part, int NB) {
  __shared__ int s[1024];
  int t = threadIdx.x;
  int v = (t < NB) ? part[t] : 0;
  s[t] = v;
#pragma unroll
  for (int off = 1; off < 1024; off <<= 1) {
    __syncthreads();
    int u = (t >= off) ? s[t - off] : 0;
    __syncthreads();
    s[t] += u;
  }
  if (t < NB) part[t] = s[t] - v;
  if (t == 1023) part[NB] = s[1023];
}

__global__ void k_scanC(int* __restrict__ offs, const int* __restrict__ part, int N, int NB) {
  int i = blockIdx.x * 256 + threadIdx.x;
  if (i < N) offs[i] += part[i >> 8];
  else if (i == N) offs[N] = part[NB];
}

// partition edges into dst-buckets; per-(block,bucket) runs exact (scanned hist)
__global__ __launch_bounds__(256) void k_part(const int* __restrict__ ei,
                                              const int* __restrict__ histoffs,
                                              unsigned* __restrict__ ebuf,
                                              int E, int NBUCK, int CH) {
  __shared__ int lcur[512];
  for (int i = threadIdx.x; i < NBUCK; i += 256)
    lcur[i] = histoffs[i * NBLK_P + blockIdx.x];
  __syncthreads();
  const int e0 = blockIdx.x * CH, e1 = min(E, e0 + CH);
  for (int e = e0 + threadIdx.x; e < e1; e += 256) {
    const int s = ei[e], d = ei[E + e];
    const int pos = atomicAdd(&lcur[d >> 9], 1);
    ebuf[pos] = ((unsigned)(d & 511) << 18) | (unsigned)s;  // N <= 262144
  }
}

// one block per bucket: per-node counts from ebuf, LDS scan -> offs, self-loops,
// LDS scatter, coalesced segment write; global fallback if segment > LDS cap.
__global__ __launch_bounds__(256) void k_build(
    const int* __restrict__ histoffs, const unsigned* __restrict__ ebuf,
    int* __restrict__ csr_src, int* __restrict__ offs, int N) {
  const int b = blockIdx.x, t = threadIdx.x;
  const int n0 = b << 9, n1 = min(N, n0 + 512), nn = n1 - n0;
  const int eb0 = histoffs[b * NBLK_P];
  const int eb1 = histoffs[(b + 1) * NBLK_P];
  const int base = eb0 + n0;
  const int L = (eb1 - eb0) + nn;
  __shared__ int cnt2[512];
  __shared__ int scn[256];
  __shared__ int cur[512];
  __shared__ int lcsr[BCAP];
  cnt2[t] = 0; cnt2[t + 256] = 0;
  __syncthreads();
  for (int e = eb0 + t; e < eb1; e += 256) atomicAdd(&cnt2[ebuf[e] >> 18], 1);
  __syncthreads();
  const int i0 = 2 * t, i1 = 2 * t + 1;
  const int a0 = (i0 < nn) ? cnt2[i0] + 1 : 0;
  const int a1 = (i1 < nn) ? cnt2[i1] + 1 : 0;
  scn[t] = a0 + a1;
  for (int off = 1; off < 256; off <<= 1) {
    __syncthreads();
    int u = (t >= off) ? scn[t - off] : 0;
    __syncthreads();
    scn[t] += u;
  }
  __syncthreads();
  const int ex = scn[t] - (a0 + a1);
  const int o0 = ex, o1 = ex + a0;
  if (i0 < nn) offs[n0 + i0] = base + o0;
  if (i1 < nn) offs[n0 + i1] = base + o1;
  if (t == 255 && n1 == N) offs[N] = base + scn[255];
  if (L <= BCAP) {
    if (i0 < nn) { lcsr[o0] = n0 + i0; cur[i0] = o0 + 1; }
    if (i1 < nn) { lcsr[o1] = n0 + i1; cur[i1] = o1 + 1; }
    __syncthreads();
    for (int e = eb0 + t; e < eb1; e += 256) {
      const unsigned pk = ebuf[e];
      const int pos = atomicAdd(&cur[pk >> 18], 1);
      lcsr[pos] = (int)(pk & 0x3FFFFu);
    }
    __syncthreads();
    for (int i = t; i < L; i += 256) csr_src[base + i] = lcsr[i];
  } else {
    if (i0 < nn) { csr_src[base + o0] = n0 + i0; cur[i0] = base + o0 + 1; }
    if (i1 < nn) { csr_src[base + o1] = n0 + i1; cur[i1] = base + o1 + 1; }
    __syncthreads();
    for (int e = eb0 + t; e < eb1; e += 256) {
      const unsigned pk = ebuf[e];
      const int pos = atomicAdd(&cur[pk >> 18], 1);
      csr_src[pos] = (int)(pk & 0x3FFFFu);
    }
  }
}

// one wave per dst node (R9 form — fetch-throughput optimum). fp16 xh gather,
// LDS-staged weights/indices, 16-edge steps w/ validity folded into weight.
__global__ __launch_bounds__(256) void k_agg(
    const int* __restrict__ csr_src, const int* __restrict__ offs,
    const float* __restrict__ a_src, const float* __restrict__ a_dst,
    const __half* __restrict__ xh, const float* __restrict__ bias,
    __half* __restrict__ xout, int N) {
  __shared__ float wls[4][64 * 5];
  __shared__ int sls[4][64];
  const int wv = threadIdx.x >> 6;
  const int wid = (blockIdx.x * 256 + threadIdx.x) >> 6;
  const int lane = threadIdx.x & 63;
  if (wid >= N) return;
  float* __restrict__ wl = wls[wv];
  int* __restrict__ sl = sls[wv];
  const int n = wid;
  const int o0 = offs[n], deg = offs[n + 1] - o0;
  const float4 dv = ((const float4*)a_dst)[n];
  const int l16 = lane & 15, g = lane >> 4, h = l16 >> 2;
  const uint4* __restrict__ xh16 = (const uint4*)xh;

  float4 sm = make_float4(0.f, 0.f, 0.f, 0.f);
  float acc[8] = {0.f, 0.f, 0.f, 0.f, 0.f, 0.f, 0.f, 0.f};

  for (int c0 = 0; c0 < deg; c0 += 64) {
    const int cl = min(64, deg - c0);
    if (lane < cl) {
      const int sj = csr_src[o0 + c0 + lane];
      const float4 av = ((const float4*)a_src)[sj];
      const float w0 = __expf(lrelu(av.x + dv.x, NS_ATT));
      const float w1 = __expf(lrelu(av.y + dv.y, NS_ATT));
      const float w2 = __expf(lrelu(av.z + dv.z, NS_ATT));
      const float w3 = __expf(lrelu(av.w + dv.w, NS_ATT));
      sm.x += w0; sm.y += w1; sm.z += w2; sm.w += w3;
      sl[lane] = sj;
      wl[lane * 5 + 0] = w0; wl[lane * 5 + 1] = w1;
      wl[lane * 5 + 2] = w2; wl[lane * 5 + 3] = w3;
    }
    for (int j = 0; j < cl; j += 16) {
      int s[4];
      float wsel[4];
      uint4 u[4];
#pragma unroll
      for (int q = 0; q < 4; ++q) {
        const int ee = j + q * 4 + g;   // always < 64
        const bool valid = ee < cl;
        const float wv_ = wl[ee * 5 + h];
        const int ss = sl[ee];
        wsel[q] = valid ? wv_ : 0.f;
        s[q] = valid ? ss : 0;
      }
#pragma unroll
      for (int q = 0; q < 4; ++q) {
        u[q] = xh16[(long)s[q] * 16 + l16];
      }
#pragma unroll
      for (int q = 0; q < 4; ++q) {
        const __half2* hp = (const __half2*)&u[q];
        const float2 f0 = __half22float2(hp[0]);
        const float2 f1 = __half22float2(hp[1]);
        const float2 f2 = __half22float2(hp[2]);
        const float2 f3 = __half22float2(hp[3]);
        acc[0] = fmaf(wsel[q], f0.x, acc[0]); acc[1] = fmaf(wsel[q], f0.y, acc[1]);
        acc[2] = fmaf(wsel[q], f1.x, acc[2]); acc[3] = fmaf(wsel[q], f1.y, acc[3]);
        acc[4] = fmaf(wsel[q], f2.x, acc[4]); acc[5] = fmaf(wsel[q], f2.y, acc[5]);
        acc[6] = fmaf(wsel[q], f3.x, acc[6]); acc[7] = fmaf(wsel[q], f3.y, acc[7]);
      }
    }
  }

#pragma unroll
  for (int m = 32; m >= 1; m >>= 1) {
    sm.x += __shfl_xor(sm.x, m);
    sm.y += __shfl_xor(sm.y, m);
    sm.z += __shfl_xor(sm.z, m);
    sm.w += __shfl_xor(sm.w, m);
  }
#pragma unroll
  for (int m = 32; m >= 16; m >>= 1) {
#pragma unroll
    for (int i = 0; i < 8; ++i) acc[i] += __shfl_xor(acc[i], m);
  }

  const float sh = (h == 0) ? sm.x : (h == 1) ? sm.y : (h == 2) ? sm.z : sm.w;
  const float inv = 1.f / (sh + 1e-16f);
  const int ch = l16 * 8 + g * 2;
  float r0 = lrelu(acc[2 * g] * inv + bias[ch], NS_ACT);
  float r1 = lrelu(acc[2 * g + 1] * inv + bias[ch + 1], NS_ACT);
  ((__half2*)(xout + (long)n * HC))[ch >> 1] = __floats2half2_rn(r0, r1);
}

// fused mean-pool + linear head: one block per graph, 512 threads (8 row streams).
__global__ __launch_bounds__(512) void k_poolfinal(
    const __half* __restrict__ xout, const int* __restrict__ batch,
    const float* __restrict__ lin_w, const float* __restrict__ lin_b,
    float* __restrict__ out, int N, int B) {
  const int b = blockIdx.x, t = threadIdx.x;
  const int lo = lowerb(batch, N, b);
  const int hi = lowerb(batch, N, b + 1);
  const int cnt = hi - lo;
  const int c2 = t & 63;     // half2 channel index
  const int rs = t >> 6;     // 8 row streams
  const __half2* __restrict__ xo2 = (const __half2*)xout;
  float ax = 0.f, ay = 0.f, bx2 = 0.f, by2 = 0.f;
  int r = lo + rs;
  for (; r + 8 < hi; r += 16) {
    float2 f0 = __half22float2(xo2[(long)r * 64 + c2]);
    float2 f1 = __half22float2(xo2[(long)(r + 8) * 64 + c2]);
    ax += f0.x; ay += f0.y; bx2 += f1.x; by2 += f1.y;
  }
  for (; r < hi; r += 8) {
    float2 f0 = __half22float2(xo2[(long)r * 64 + c2]);
    ax += f0.x; ay += f0.y;
  }
  __shared__ float2 sp[512];
  __shared__ float pl[HC];
  sp[t] = make_float2(ax + bx2, ay + by2);
  __syncthreads();
  if (t < 64) {
    float vx = 0.f, vy = 0.f;
#pragma unroll
    for (int i = 0; i < 8; ++i) {
      vx += sp[t + i * 64].x;
      vy += sp[t + i * 64].y;
    }
    const float c = fmaxf((float)cnt, 1.0f);
    pl[2 * t] = vx / c;
    pl[2 * t + 1] = vy / c;
  }
  __syncthreads();
  if (t < 10) {
    float a = lin_b[t];
    for (int k = 0; k < HC; ++k) a = fmaf(pl[k], lin_w[t * HC + k], a);
    out[b * 10 + t] = a;
  }
}

extern "C" void kernel_launch(void* const* d_in, const int* in_sizes, int n_in,
                              void* d_out, int out_size, void* d_ws, size_t ws_size,
                              hipStream_t stream) {
  const float* x = (const float*)d_in[0];
  const int* ei = (const int*)d_in[1];
  const int* batch = (const int*)d_in[2];
  const float* Wm = (const float*)d_in[4];
  const float* att_s = (const float*)d_in[5];
  const float* att_d = (const float*)d_in[6];
  const float* bias = (const float*)d_in[7];
  const float* lin_w = (const float*)d_in[8];
  const float* lin_b = (const float*)d_in[9];
  float* out = (float*)d_out;

  const int N = in_sizes[2];
  const int E = in_sizes[1] / 2;
  const int B = out_size / 10;
  const int NBUCK = (N + 511) >> 9;        // dst buckets (<=512)
  const int M = NBUCK * NBLK_P;            // hist entries
  const int NB2 = (M + 255) / 256;         // hist-scan blocks (<=1024)
  const int CH = (E + NBLK_P - 1) / NBLK_P;

  char* p = (char*)d_ws;
  auto carve = [&](size_t bytes) {
    void* r = (void*)p;
    p += (bytes + 255) & ~(size_t)255;
    return r;
  };
  __half* xh = (__half*)carve((size_t)N * HC * 2);
  __half* xout = (__half*)carve((size_t)N * HC * 2);
  float* a_src = (float*)carve((size_t)N * NHEAD * 4);
  float* a_dst = (float*)carve((size_t)N * NHEAD * 4);
  int* offs = (int*)carve((size_t)(N + 1) * 4);
  int* csr_src = (int*)carve((size_t)(N + (size_t)E) * 4);
  _Float16* Wh = (_Float16*)carve((size_t)9 * 4 * 64 * 8 * 2);

  // alias partition scratch into xout (consumed by k_build before k_agg writes xout)
  char* q = (char*)xout;
  auto carve2 = [&](size_t bytes) {
    void* r = (void*)q;
    q += (bytes + 255) & ~(size_t)255;
    return r;
  };
  unsigned* ebuf = (unsigned*)carve2((size_t)E * 4);
  int* hist = (int*)carve2((size_t)M * 4);
  int* histoffs = (int*)carve2((size_t)(M + 1) * 4);
  int* part2 = (int*)carve2((size_t)(NB2 + 2) * 4);

  k_hw<<<NBLK_P + 9, 256, 0, stream>>>(ei, hist, E, NBUCK, CH, Wm, att_s, att_d, Wh);
  k_xw<<<(N + 63) / 64, 256, 0, stream>>>(x, Wh, (_Float16*)xh, a_src, a_dst, N);
  k_scanA<<<NB2, 256, 0, stream>>>(hist, histoffs, part2, M);
  k_scanB<<<1, 1024, 0, stream>>>(part2, NB2);
  k_scanC<<<(M + 256) / 256, 256, 0, stream>>>(histoffs, part2, M, NB2);
  k_part<<<NBLK_P, 256, 0, stream>>>(ei, histoffs, ebuf, E, NBUCK, CH);
  k_build<<<NBUCK, 256, 0, stream>>>(histoffs, ebuf, csr_src, offs, N);
  k_agg<<<(N + 3) / 4, 256, 0, stream>>>(csr_src, offs, a_src, a_dst, xh, bias, xout, N);
  k_poolfinal<<<B, 512, 0, stream>>>(xout, batch, lin_w, lin_b, out, N, B);
}